// Round 13
// baseline (588.949 us; speedup 1.0000x reference)
//
#include <hip/hip_runtime.h>
#include <hip/hip_bf16.h>
#include <math.h>

#define NN 32768
#define EE 524288
#define LL 6

typedef __attribute__((ext_vector_type(8))) short short8;
typedef __attribute__((ext_vector_type(4))) float floatx4;
typedef __attribute__((ext_vector_type(4))) float fx4;
typedef __attribute__((ext_vector_type(2))) float fx2;

union U16x8 { short8 v; unsigned short u[8]; };

__device__ __forceinline__ unsigned short f2bf(float x) {
    union { float f; unsigned int u; } v; v.f = x;
    unsigned int r = v.u + 0x7fffu + ((v.u >> 16) & 1u);
    return (unsigned short)(r >> 16);
}
__device__ __forceinline__ float bf2f(unsigned short h) {
    union { unsigned int u; float f; } v; v.u = (unsigned int)h << 16;
    return v.f;
}

// ---------------- preprocessing ----------------

__global__ void deg_kernel(const int* __restrict__ dst, int* __restrict__ deg) {
    int i = (blockIdx.x * 256 + threadIdx.x) * 4;
    int4 d = *(const int4*)(dst + i);
    atomicAdd(&deg[d.x], 1);
    atomicAdd(&deg[d.y], 1);
    atomicAdd(&deg[d.z], 1);
    atomicAdd(&deg[d.w], 1);
}

// degree histogram (128 bins; Poisson(16) max ~45, cap is safety only)
__global__ void hist_kernel(const int* __restrict__ deg, int* __restrict__ hist) {
    int n = blockIdx.x * 256 + threadIdx.x;
    int b = deg[n]; b = b > 127 ? 127 : b;
    atomicAdd(&hist[b], 1);
}

// exclusive scans of node-count and edge-count per bin
__global__ __launch_bounds__(128) void binscan_kernel(const int* __restrict__ hist,
                                                      int* __restrict__ binBase,
                                                      int* __restrict__ edgeBase) {
    if (threadIdx.x == 0) {
        int accN = 0, accE = 0;
        for (int b = 0; b < 128; ++b) {
            binBase[b] = accN;
            edgeBase[b] = accE;
            int c = hist[b];
            accN += c;
            accE += c * b;
        }
    }
}

// rank assignment + permuted-space row_ptr (closed form: all nodes in a bin share
// one degree) + zero the per-rank fill counters
__global__ void rank_kernel(const int* __restrict__ deg, const int* __restrict__ binBase,
                            const int* __restrict__ edgeBase, int* __restrict__ binCnt,
                            int* __restrict__ rank, int* __restrict__ row_ptrP,
                            int* __restrict__ cnt) {
    int n = blockIdx.x * 256 + threadIdx.x;
    int b = deg[n]; b = b > 127 ? 127 : b;
    int r = binBase[b] + atomicAdd(&binCnt[b], 1);
    rank[n] = r;
    row_ptrP[r] = edgeBase[b] + (r - binBase[b]) * b;
    cnt[r] = 0;
    if (n == 0) row_ptrP[NN] = EE;
}

// CSR fill in rank space: 8-B scatter {edge id, rank[src]}
__global__ void fill_kernel(const int* __restrict__ src, const int* __restrict__ dst,
                            const int* __restrict__ rank, const int* __restrict__ row_ptrP,
                            int* __restrict__ cnt, int2* __restrict__ sedge) {
    int e = blockIdx.x * 256 + threadIdx.x;
    if (e >= EE) return;
    int rd = rank[dst[e]];
    int pos = row_ptrP[rd] + atomicAdd(&cnt[rd], 1);
    sedge[pos] = make_int2(e, rank[src[e]]);
}

// One prep kernel: blocks 0..6 = wprep tiles; block 7 = aeB frags + w1c;
// blocks 8..13 = vsmake[l]; blocks 14..45 = zero deg; block 46 = zero hist/binCnt
__global__ __launch_bounds__(256) void smallprep_kernel(
    const float* __restrict__ lin_W, const float* __restrict__ head_W1,
    const float* __restrict__ lin_edge_W, const float* __restrict__ att_edge,
    const float* __restrict__ att_src, const float* __restrict__ att_dst,
    unsigned short* __restrict__ gBhi, unsigned short* __restrict__ gBlo,
    unsigned short* __restrict__ aeBhi, unsigned short* __restrict__ aeBlo,
    float* __restrict__ vs, float* __restrict__ vvd,
    unsigned short* __restrict__ w1chi, unsigned short* __restrict__ w1clo,
    int* __restrict__ deg, int* __restrict__ hist, int* __restrict__ binCnt) {
    __shared__ float svb[384];
    int bb = blockIdx.x;
    int tid = threadIdx.x;
    if (bb < 7) {
        unsigned short* dh = gBhi + (size_t)bb * 128 * 64;
        unsigned short* dl = gBlo + (size_t)bb * 128 * 64;
        if (bb < 6) {
            int n2 = tid & 63, kh = tid >> 6;
            U16x8 hh[4], ll[4];
            for (int kk = 0; kk < 32; ++kk) {
                int j = kh * 32 + kk;
                int h = j >> 6, k = j & 63;
                float wv = 0.5f * lin_W[((size_t)bb * 64 + k) * 128 + h * 64 + n2];
                unsigned short h16 = f2bf(wv);
                hh[kk >> 3].u[kk & 7] = h16;
                ll[kk >> 3].u[kk & 7] = f2bf(wv - bf2f(h16));
            }
#pragma unroll
            for (int c = 0; c < 4; ++c) {
                int cg = kh * 4 + c;
                int off = n2 * 128 + ((cg ^ (n2 & 15)) << 3);
                *(short8*)(dh + off) = hh[c].v;
                *(short8*)(dl + off) = ll[c].v;
            }
        } else {
            int n = tid & 127, kh = tid >> 7;
            U16x8 hh[4], ll[4];
            for (int kk = 0; kk < 32; ++kk) {
                int k = kh * 32 + kk;
                float wv = (n < 64) ? head_W1[k * 64 + n] : head_W1[(64 + k) * 64 + (n - 64)];
                unsigned short h16 = f2bf(wv);
                hh[kk >> 3].u[kk & 7] = h16;
                ll[kk >> 3].u[kk & 7] = f2bf(wv - bf2f(h16));
            }
#pragma unroll
            for (int c = 0; c < 4; ++c) {
                int cg = kh * 4 + c;
                int off = n * 64 + ((cg ^ (n & 7)) << 3);
                *(short8*)(dh + off) = hh[c].v;
                *(short8*)(dl + off) = ll[c].v;
            }
        }
    } else if (bb == 7) {
        for (int t = tid; t < 384; t += 256) {
            int l = t / 64; int r = t & 63; int ed = r >> 1; int hh = r & 1;
            const float* w = lin_edge_W + l * 32 * 128 + ed * 128 + hh * 64;
            const float* a = att_edge + l * 128 + hh * 64;
            float s = 0.f;
#pragma unroll 8
            for (int c = 0; c < 64; ++c) s += w[c] * a[c];
            svb[t] = s;
        }
        int n = tid & 63, kc = tid >> 6;
#pragma unroll
        for (int j = 0; j < 8; ++j) {
            int k = kc * 8 + j;
            float wv = head_W1[(128 + k) * 64 + n];
            unsigned short h16 = f2bf(wv);
            w1chi[n * 32 + k] = h16;
            w1clo[n * 32 + k] = f2bf(wv - bf2f(h16));
        }
        __syncthreads();
        if (tid < 64) {
            int n2 = tid & 15, q = tid >> 4;
            U16x8 hi, lo;
#pragma unroll
            for (int i = 0; i < 8; ++i) {
                int k = q * 8 + i;
                float val = (n2 < 12) ? svb[(n2 >> 1) * 64 + k * 2 + (n2 & 1)] : 0.f;
                unsigned short h16 = f2bf(val);
                hi.u[i] = h16;
                lo.u[i] = f2bf(val - bf2f(h16));
            }
            *(short8*)(aeBhi + tid * 8) = hi.v;
            *(short8*)(aeBlo + tid * 8) = lo.v;
        }
    } else if (bb < 14) {
        int l = bb - 8;
        int sel = tid >> 7, idx = tid & 127;
        int h = idx >> 6, k = idx & 63;
        const float* att = (sel ? att_dst : att_src) + l * 128 + h * 64;
        const float* wr = lin_W + ((size_t)l * 64 + k) * 128 + h * 64;
        float s = 0.f;
#pragma unroll 8
        for (int c = 0; c < 64; ++c) s += wr[c] * att[c];
        (sel ? vvd : vs)[l * 128 + idx] = s;
    } else if (bb < 46) {
        int i = (bb - 14) * 1024 + tid * 4;
        *(int4*)(deg + i) = make_int4(0, 0, 0, 0);
    } else {
        if (tid < 128) { hist[tid] = 0; binCnt[tid] = 0; }
    }
}

// CSR-order a_e: gathers edge_attr rows (random 128-B, L3-backed), MFMA for all 12
// dots. Writes srcc (rank-space, 4 B/edge) + per-layer float2 aeF (8 B/edge).
__global__ __launch_bounds__(256) void ae_csr_kernel(
    const float* __restrict__ edge_attr, const int2* __restrict__ sedge,
    const unsigned short* __restrict__ aeBhi, const unsigned short* __restrict__ aeBlo,
    float* __restrict__ aeF, int* __restrict__ srcc) {
    __shared__ float tr[4][64 * 13];
    int tid = threadIdx.x;
    int w = tid >> 6, lane = tid & 63;
    int p0 = blockIdx.x * 256 + w * 64;
    short8 bhi = *(const short8*)(aeBhi + lane * 8);
    short8 blo = *(const short8*)(aeBlo + lane * 8);
    int r = lane & 15, q = lane >> 4;
    float* trw = tr[w];
#pragma unroll
    for (int t = 0; t < 4; ++t) {
        int eg = sedge[p0 + t * 16 + r].x;
        const fx4* p = (const fx4*)(edge_attr + (size_t)eg * 32 + q * 8);
        fx4 f0 = p[0], f1 = p[1];
        float av[8] = {f0.x, f0.y, f0.z, f0.w, f1.x, f1.y, f1.z, f1.w};
        U16x8 hi, lo;
#pragma unroll
        for (int jj = 0; jj < 8; ++jj) {
            unsigned short h16 = f2bf(av[jj]);
            hi.u[jj] = h16;
            lo.u[jj] = f2bf(av[jj] - bf2f(h16));
        }
        floatx4 acc = {};
        acc = __builtin_amdgcn_mfma_f32_16x16x32_bf16(lo.v, bhi, acc, 0, 0, 0);
        acc = __builtin_amdgcn_mfma_f32_16x16x32_bf16(hi.v, blo, acc, 0, 0, 0);
        acc = __builtin_amdgcn_mfma_f32_16x16x32_bf16(hi.v, bhi, acc, 0, 0, 0);
        if (r < 12) {
#pragma unroll
            for (int rr = 0; rr < 4; ++rr)
                trw[(t * 16 + q * 4 + rr) * 13 + r] = acc[rr];
        }
    }
    // same-wave DS order: no barrier needed
    int2 sl = sedge[p0 + lane];
    srcc[p0 + lane] = sl.y;
#pragma unroll
    for (int l = 0; l < LL; ++l) {
        fx2 rec;
        rec.x = trw[lane * 13 + l * 2];
        rec.y = trw[lane * 13 + l * 2 + 1];
        __builtin_nontemporal_store(rec, (fx2*)(aeF + ((size_t)l * EE + p0 + lane) * 2));
    }
}

// embed + layer-0 LN/affine + layer-0 attention dots; outputs scattered to rank space
__global__ __launch_bounds__(256) void embed_ln_kernel(
    const float* __restrict__ x, const float* __restrict__ W, const float* __restrict__ b,
    const float* __restrict__ ln_g, const float* __restrict__ ln_b,
    const float* __restrict__ mg, const float* __restrict__ mb,
    const float* __restrict__ vs0, const float* __restrict__ vd0,
    const int* __restrict__ rank,
    unsigned short* __restrict__ hm_bf, float* __restrict__ a_s, float* __restrict__ a_d) {
    __shared__ float xr[4][64];
    int w = threadIdx.x >> 6, j = threadIdx.x & 63;
    int n = blockIdx.x * 4 + w;
    xr[w][j] = x[(size_t)n * 64 + j];
    __syncthreads();
    float acc = b[j];
#pragma unroll 8
    for (int k = 0; k < 64; ++k) acc += xr[w][k] * W[k * 64 + j];
    float s = acc, sq = acc * acc;
    for (int off = 1; off < 64; off <<= 1) { s += __shfl_xor(s, off); sq += __shfl_xor(sq, off); }
    float mu = s * (1.f / 64.f);
    float var = sq * (1.f / 64.f) - mu * mu;
    float rs = rsqrtf(var + 1e-5f);
    float hm = mg[j] * (ln_g[j] * (acc - mu) * rs + ln_b[j]) + mb[j];
    int rp = rank[n];
    hm_bf[(size_t)rp * 64 + j] = f2bf(hm);
    float s0 = hm * vs0[j], s1 = hm * vs0[64 + j];
    float d0 = hm * vd0[j], d1 = hm * vd0[64 + j];
    for (int off = 1; off < 64; off <<= 1) {
        s0 += __shfl_xor(s0, off); s1 += __shfl_xor(s1, off);
        d0 += __shfl_xor(d0, off); d1 += __shfl_xor(d1, off);
    }
    if (j == 0) {
        a_s[rp * 2] = s0; a_s[rp * 2 + 1] = s1;
        a_d[rp * 2] = d0; a_d[rp * 2 + 1] = d1;
    }
}

__device__ __forceinline__ void fma8h(uint4 pv, float w, float* a) {
    unsigned int u[4] = {pv.x, pv.y, pv.z, pv.w};
#pragma unroll
    for (int q = 0; q < 4; ++q) {
        union { unsigned int x; float f; } lo, hi;
        lo.x = u[q] << 16; hi.x = u[q] & 0xffff0000u;
        a[2 * q]     += w * lo.f;
        a[2 * q + 1] += w * hi.f;
    }
}

// Dual-head aggregation for node n (rank space): 8 lanes per node, lane ch owns
// channel pair ch for BOTH heads.
__device__ __forceinline__ void agg_node2(
    int n, int ch, const uint4* hmv, const float2* as2,
    const float* ad_in, const float* aeLl, const int* srcc,
    const int* row_ptr, float* sg, U16x8& hb0, U16x8& hb1) {
    float2 adn = ((const float2*)ad_in)[n];
    float2 asn = as2[n];
    uint4 pvself = hmv[(size_t)n * 8 + ch];
    int beg = row_ptr[n], end = row_ptr[n + 1];
    int degn = end - beg;
    float acc0[8] = {}, acc1[8] = {};
    float den0 = 0.f, den1 = 0.f, aex = 0.f, aey = 0.f;
    for (int base = 0; base < degn; base += 16) {
        int cnt = degn - base; cnt = cnt > 16 ? 16 : cnt;
        // phase 1: lane stages slots ch and ch+8 of this 16-chunk
#pragma unroll
        for (int pass = 0; pass < 2; ++pass) {
            int s = pass * 8 + ch;
            float w0v = 0.f, w1v = 0.f;
            int sval = 0;
            if (s < cnt) {
                int idx = beg + base + s;
                int sv = srcc[idx];
                fx2 ae = *(const fx2*)(aeLl + (size_t)idx * 2);
                float2 as = as2[sv];
                aex += ae.x; aey += ae.y;
                float al0 = as.x + adn.x + ae.x; al0 = al0 > 0.f ? al0 : 0.2f * al0;
                float al1 = as.y + adn.y + ae.y; al1 = al1 > 0.f ? al1 : 0.2f * al1;
                w0v = __expf(al0);
                w1v = __expf(al1);
                sval = sv;
            }
            float4 st;
            st.x = __int_as_float(sval); st.y = w0v; st.z = w1v; st.w = 0.f;
            *(float4*)(sg + s * 4) = st;   // same-wave in-order DS pipe
        }
        // phase 2: 8 slots per step; group of 8 lanes fetches one full node row
        int c8 = (cnt + 7) & ~7;
        for (int s = 0; s < c8; s += 8) {
            float4 m[8];
#pragma unroll
            for (int u = 0; u < 8; ++u) m[u] = *(const float4*)(sg + (s + u) * 4);
            uint4 p[8];
#pragma unroll
            for (int u = 0; u < 8; ++u) p[u] = hmv[(size_t)__float_as_int(m[u].x) * 8 + ch];
#pragma unroll
            for (int u = 0; u < 8; ++u) {
                den0 += m[u].y; fma8h(p[u], m[u].y, acc0);
                den1 += m[u].z; fma8h(p[u], m[u].z, acc1);
            }
        }
    }
    // reduce aex/aey over the 8-lane group
#pragma unroll
    for (int m2 = 1; m2 < 8; m2 <<= 1) {
        aex += __shfl_xor(aex, m2);
        aey += __shfl_xor(aey, m2);
    }
    float invd = 1.f / fmaxf((float)degn, 1.f);
    float al0 = asn.x + adn.x + aex * invd; al0 = al0 > 0.f ? al0 : 0.2f * al0;
    float al1 = asn.y + adn.y + aey * invd; al1 = al1 > 0.f ? al1 : 0.2f * al1;
    float ws0 = __expf(al0), ws1 = __expf(al1);
    den0 += ws0; den1 += ws1;
    fma8h(pvself, ws0, acc0);
    fma8h(pvself, ws1, acc1);
    float inv0 = 1.f / (den0 + 1e-16f), inv1 = 1.f / (den1 + 1e-16f);
#pragma unroll
    for (int q = 0; q < 8; ++q) {
        hb0.u[q] = f2bf(acc0[q] * inv0);
        hb1.u[q] = f2bf(acc1[q] * inv1);
    }
}

// ---------------- fused layer (0..4): rank space; heavy blocks scheduled first ----
__global__ __launch_bounds__(512) void fused_post(
    const unsigned short* __restrict__ hm_in, const float* __restrict__ as_in,
    const float* __restrict__ ad_in, const float* __restrict__ aeLl,
    const int* __restrict__ srcc, const int* __restrict__ row_ptr,
    const unsigned short* __restrict__ gBhi, const unsigned short* __restrict__ gBlo,
    const float* __restrict__ bias, const float* __restrict__ ln_g,
    const float* __restrict__ ln_b, const float* __restrict__ mg,
    const float* __restrict__ mb, const float* __restrict__ vsn,
    const float* __restrict__ vdn, unsigned short* __restrict__ hm_out,
    float* __restrict__ as_out, float* __restrict__ ad_out) {
    __shared__ char smem[49152];                           // 48 KB
    unsigned short* Ahi = (unsigned short*)smem;           // 16 KB [64][128]
    float* stgAll = (float*)(smem + 16384);                // 16 KB during aggregation
    unsigned short* Bhi = (unsigned short*)(smem + 16384); // aliased after
    unsigned short* Blo = (unsigned short*)(smem + 32768);
    int tid = threadIdx.x;
    int w = tid >> 6, lane = tid & 63;
    int g = lane >> 3, ch = lane & 7;
    const float2* as2 = (const float2*)as_in;
    const uint4* hmv = (const uint4*)hm_in;
    float* sg = stgAll + (w * 8 + g) * 64;   // 16 slots x 4 floats per (wave,group)
    int nb = NN - 64 - blockIdx.x * 64;      // heavy (high-degree) blocks first

    {
        int m = w * 8 + g;
        U16x8 hb0, hb1;
        agg_node2(nb + m, ch, hmv, as2, ad_in, aeLl, srcc, row_ptr, sg, hb0, hb1);
        *(short8*)(Ahi + m * 128 + ((ch ^ (m & 15)) << 3)) = hb0.v;
        *(short8*)(Ahi + m * 128 + (((8 + ch) ^ (m & 15)) << 3)) = hb1.v;
    }
    __syncthreads();   // stg dead; Ahi complete
    {
        const uint4* sh = (const uint4*)gBhi;
        const uint4* sl = (const uint4*)gBlo;
        for (int i = tid; i < 1024; i += 512) {
            ((uint4*)Bhi)[i] = sh[i];
            ((uint4*)Blo)[i] = sl[i];
        }
    }
    __syncthreads();

    if (w < 4) {
        int col = lane & 15, quad = lane >> 4;
        int m = w * 16 + col;
        floatx4 acc[4] = {};
#pragma unroll
        for (int s = 0; s < 4; ++s) {
            int ca = (quad + 4 * s) ^ col;
            short8 ahi = *(const short8*)(Ahi + m * 128 + ca * 8);
#pragma unroll
            for (int t = 0; t < 4; ++t) {
                int off = (t * 16 + col) * 128 + ca * 8;
                short8 bhi = *(const short8*)(Bhi + off);
                short8 blo = *(const short8*)(Blo + off);
                acc[t] = __builtin_amdgcn_mfma_f32_16x16x32_bf16(ahi, blo, acc[t], 0, 0, 0);
                acc[t] = __builtin_amdgcn_mfma_f32_16x16x32_bf16(ahi, bhi, acc[t], 0, 0, 0);
            }
        }
        int nodebase = nb + w * 16;
        float bv[4];
#pragma unroll
        for (int t = 0; t < 4; ++t) bv[t] = bias[t * 16 + col];
        float vsv[4], vsv1[4], vdv[4], vdv1[4], lg[4], lb[4], mgv[4], mbv[4];
#pragma unroll
        for (int t = 0; t < 4; ++t) {
            int c = t * 16 + col;
            vsv[t] = vsn[c]; vsv1[t] = vsn[64 + c];
            vdv[t] = vdn[c]; vdv1[t] = vdn[64 + c];
            lg[t] = ln_g[c]; lb[t] = ln_b[c];
            mgv[t] = mg[c]; mbv[t] = mb[c];
        }
#pragma unroll
        for (int r = 0; r < 4; ++r) {
            int node = nodebase + quad * 4 + r;
            float hv[4];
            float s = 0.f, sq = 0.f;
#pragma unroll
            for (int t = 0; t < 4; ++t) {
                float v = acc[t][r] + bv[t];
                v = v > 0.f ? v : 0.f;
                hv[t] = v;
                s += v; sq += v * v;
            }
            for (int off = 1; off < 16; off <<= 1) { s += __shfl_xor(s, off); sq += __shfl_xor(sq, off); }
            float mu = s * (1.f / 64.f);
            float var = sq * (1.f / 64.f) - mu * mu;
            float rs = rsqrtf(var + 1e-5f);
            float s0 = 0.f, s1 = 0.f, d0 = 0.f, d1 = 0.f;
#pragma unroll
            for (int t = 0; t < 4; ++t) {
                float hmval = mgv[t] * (lg[t] * (hv[t] - mu) * rs + lb[t]) + mbv[t];
                hm_out[(size_t)node * 64 + t * 16 + col] = f2bf(hmval);
                s0 += hmval * vsv[t]; s1 += hmval * vsv1[t];
                d0 += hmval * vdv[t]; d1 += hmval * vdv1[t];
            }
            for (int off = 1; off < 16; off <<= 1) {
                s0 += __shfl_xor(s0, off); s1 += __shfl_xor(s1, off);
                d0 += __shfl_xor(d0, off); d1 += __shfl_xor(d1, off);
            }
            if (col == 0) {
                as_out[node * 2] = s0; as_out[node * 2 + 1] = s1;
                ad_out[node * 2] = d0; ad_out[node * 2 + 1] = d1;
            }
        }
    }
}

// ---------------- fused last layer (rank space): agg -> h=relu(A@B5+b) -> uv ----
__global__ __launch_bounds__(512) void fused_uv(
    const unsigned short* __restrict__ hm_in, const float* __restrict__ as_in,
    const float* __restrict__ ad_in, const float* __restrict__ aeLl,
    const int* __restrict__ srcc, const int* __restrict__ row_ptr,
    const unsigned short* __restrict__ gB5hi, const unsigned short* __restrict__ gB5lo,
    const float* __restrict__ bias,
    const unsigned short* __restrict__ gB6hi, const unsigned short* __restrict__ gB6lo,
    unsigned short* __restrict__ uv) {
    __shared__ char smem[49152];
    unsigned short* Ahi  = (unsigned short*)smem;            // stage1 A: 64x128 (16 KB)
    float* stgAll        = (float*)(smem + 16384);           // agg staging (16 KB, aliased)
    unsigned short* B5hi = (unsigned short*)(smem + 16384);
    unsigned short* B5lo = (unsigned short*)(smem + 32768);
    unsigned short* A2hi = (unsigned short*)smem;            // stage2 A (aliases Ahi)
    unsigned short* A2lo = (unsigned short*)(smem + 8192);
    unsigned short* B6hi = (unsigned short*)(smem + 16384);
    unsigned short* B6lo = (unsigned short*)(smem + 32768);
    int tid = threadIdx.x;
    int w = tid >> 6, lane = tid & 63;
    int g = lane >> 3, ch = lane & 7;
    const float2* as2 = (const float2*)as_in;
    const uint4* hmv = (const uint4*)hm_in;
    float* sg = stgAll + (w * 8 + g) * 64;
    int nb = NN - 64 - blockIdx.x * 64;      // heavy blocks first

    {
        int m = w * 8 + g;
        U16x8 hb0, hb1;
        agg_node2(nb + m, ch, hmv, as2, ad_in, aeLl, srcc, row_ptr, sg, hb0, hb1);
        *(short8*)(Ahi + m * 128 + ((ch ^ (m & 15)) << 3)) = hb0.v;
        *(short8*)(Ahi + m * 128 + (((8 + ch) ^ (m & 15)) << 3)) = hb1.v;
    }
    __syncthreads();
    {
        const uint4* sh = (const uint4*)gB5hi;
        const uint4* sl = (const uint4*)gB5lo;
        for (int i = tid; i < 1024; i += 512) {
            ((uint4*)B5hi)[i] = sh[i];
            ((uint4*)B5lo)[i] = sl[i];
        }
    }
    __syncthreads();

    int col = lane & 15, quad = lane >> 4;
    int m = w * 16 + col;
    floatx4 acc[4] = {};
    if (w < 4) {
#pragma unroll
        for (int s = 0; s < 4; ++s) {
            int ca = (quad + 4 * s) ^ col;
            short8 ahi = *(const short8*)(Ahi + m * 128 + ca * 8);
#pragma unroll
            for (int t = 0; t < 4; ++t) {
                int off = (t * 16 + col) * 128 + ca * 8;
                short8 bhi = *(const short8*)(B5hi + off);
                short8 blo = *(const short8*)(B5lo + off);
                acc[t] = __builtin_amdgcn_mfma_f32_16x16x32_bf16(ahi, blo, acc[t], 0, 0, 0);
                acc[t] = __builtin_amdgcn_mfma_f32_16x16x32_bf16(ahi, bhi, acc[t], 0, 0, 0);
            }
        }
    }
    __syncthreads();  // stage1 LDS (Ahi + B5) fully consumed
    if (w < 4) {
        float bv[4];
#pragma unroll
        for (int t = 0; t < 4; ++t) bv[t] = bias[t * 16 + col];
#pragma unroll
        for (int t = 0; t < 4; ++t) {
            int c = t * 16 + col;
            int cg = c >> 3, cr = c & 7;
#pragma unroll
            for (int r = 0; r < 4; ++r) {
                float v = acc[t][r] + bv[t];
                v = v > 0.f ? v : 0.f;
                int i = w * 16 + quad * 4 + r;
                int off = i * 64 + ((cg ^ (i & 7)) << 3) + cr;
                unsigned short hhv = f2bf(v);
                A2hi[off] = hhv;
                A2lo[off] = f2bf(v - bf2f(hhv));
            }
        }
    }
    for (int i = tid; i < 1024; i += 512) {
        ((uint4*)B6hi)[i] = ((const uint4*)gB6hi)[i];
        ((uint4*)B6lo)[i] = ((const uint4*)gB6lo)[i];
    }
    __syncthreads();

    if (w < 4) {
        floatx4 acc2[8] = {};
#pragma unroll
        for (int s = 0; s < 2; ++s) {
            int ca = (quad + 4 * s) ^ (col & 7);
            short8 a2h = *(const short8*)(A2hi + m * 64 + ca * 8);
            short8 a2l = *(const short8*)(A2lo + m * 64 + ca * 8);
#pragma unroll
            for (int t = 0; t < 8; ++t) {
                int off = (t * 16 + col) * 64 + ca * 8;
                short8 bh = *(const short8*)(B6hi + off);
                short8 bl = *(const short8*)(B6lo + off);
                acc2[t] = __builtin_amdgcn_mfma_f32_16x16x32_bf16(a2l, bh, acc2[t], 0, 0, 0);
                acc2[t] = __builtin_amdgcn_mfma_f32_16x16x32_bf16(a2h, bl, acc2[t], 0, 0, 0);
                acc2[t] = __builtin_amdgcn_mfma_f32_16x16x32_bf16(a2h, bh, acc2[t], 0, 0, 0);
            }
        }
        int nodebase = nb + w * 16;
#pragma unroll
        for (int t = 0; t < 8; ++t)
#pragma unroll
            for (int r = 0; r < 4; ++r)
                uv[(size_t)(nodebase + quad * 4 + r) * 128 + t * 16 + col] = f2bf(acc2[t][r]);
    }
}

// ---------------- edge output head: uv rows looked up via rank[] ----------------
__global__ __launch_bounds__(256) void head2_kernel(
    const unsigned short* __restrict__ uv, const int* __restrict__ src,
    const int* __restrict__ dst, const int* __restrict__ rank,
    const float* __restrict__ edge_attr,
    const unsigned short* __restrict__ w1chi, const unsigned short* __restrict__ w1clo,
    const float* __restrict__ b1, const float* __restrict__ W2,
    const float* __restrict__ b2, float* __restrict__ out) {
    __shared__ float g[64][68];
    __shared__ unsigned short Abf[64 * 40];
    __shared__ unsigned short Bh[64 * 40], Bl[64 * 40];
    __shared__ int sA[64], dA[64];
    int tid = threadIdx.x;
    int base = blockIdx.x * 64;
    if (tid < 64) sA[tid] = rank[src[base + tid]];
    else if (tid < 128) dA[tid - 64] = rank[dst[base + tid - 64]];
    {
        int n = tid >> 2, c = tid & 3;
        *(short8*)(Bh + n * 40 + c * 8) = *(const short8*)(w1chi + n * 32 + c * 8);
        *(short8*)(Bl + n * 40 + c * 8) = *(const short8*)(w1clo + n * 32 + c * 8);
    }
    {
        int e = tid >> 2, q = tid & 3;
        const fx4* p = (const fx4*)(edge_attr + (size_t)(base + e) * 32 + q * 8);
        fx4 f0 = __builtin_nontemporal_load(p);
        fx4 f1 = __builtin_nontemporal_load(p + 1);
        float av[8] = {f0.x, f0.y, f0.z, f0.w, f1.x, f1.y, f1.z, f1.w};
        U16x8 cv;
#pragma unroll
        for (int jj = 0; jj < 8; ++jj) cv.u[jj] = f2bf(av[jj]);
        *(short8*)(Abf + e * 40 + q * 8) = cv.v;
    }
    __syncthreads();
    {
        int e = tid >> 2, q = tid & 3;
        const uint4* su = (const uint4*)(uv + (size_t)sA[e] * 128);
        const uint4* dv = (const uint4*)(uv + (size_t)dA[e] * 128);
        uint4 U0 = su[2 * q], U1 = su[2 * q + 1];
        uint4 V0 = dv[8 + 2 * q], V1 = dv[9 + 2 * q];
        const float4* b1p = (const float4*)(b1 + q * 16);
        float bb[16];
#pragma unroll
        for (int jj = 0; jj < 4; ++jj) {
            float4 b4 = b1p[jj];
            bb[4 * jj] = b4.x; bb[4 * jj + 1] = b4.y; bb[4 * jj + 2] = b4.z; bb[4 * jj + 3] = b4.w;
        }
        unsigned int uw[8] = {U0.x, U0.y, U0.z, U0.w, U1.x, U1.y, U1.z, U1.w};
        unsigned int vw[8] = {V0.x, V0.y, V0.z, V0.w, V1.x, V1.y, V1.z, V1.w};
        float* gr = &g[e][q * 16];
#pragma unroll
        for (int jj = 0; jj < 8; ++jj) {
            gr[2 * jj] = bf2f((unsigned short)(uw[jj] & 0xffff)) +
                         bf2f((unsigned short)(vw[jj] & 0xffff)) + bb[2 * jj];
            gr[2 * jj + 1] = bf2f((unsigned short)(uw[jj] >> 16)) +
                             bf2f((unsigned short)(vw[jj] >> 16)) + bb[2 * jj + 1];
        }
    }
    __syncthreads();

    int lane = tid & 63, w = tid >> 6, col = lane & 15, quad = lane >> 4;
    short8 a = *(const short8*)(Abf + (w * 16 + col) * 40 + quad * 8);
    floatx4 acc[4] = {};
#pragma unroll
    for (int t = 0; t < 4; ++t) {
        int off = (t * 16 + col) * 40 + quad * 8;
        short8 bh = *(const short8*)(Bh + off);
        short8 bl = *(const short8*)(Bl + off);
        acc[t] = __builtin_amdgcn_mfma_f32_16x16x32_bf16(a, bl, acc[t], 0, 0, 0);
        acc[t] = __builtin_amdgcn_mfma_f32_16x16x32_bf16(a, bh, acc[t], 0, 0, 0);
    }
    float sv[4] = {0.f, 0.f, 0.f, 0.f};
#pragma unroll
    for (int t = 0; t < 4; ++t) {
        float w2v = W2[t * 16 + col];
#pragma unroll
        for (int r = 0; r < 4; ++r) {
            float hid = acc[t][r] + g[w * 16 + quad * 4 + r][t * 16 + col];
            hid = hid > 0.f ? hid : 0.f;
            sv[r] += hid * w2v;
        }
    }
    float b2v = b2[0];
#pragma unroll
    for (int r = 0; r < 4; ++r) {
        float v = sv[r];
        v += __shfl_xor(v, 1);
        v += __shfl_xor(v, 2);
        v += __shfl_xor(v, 4);
        v += __shfl_xor(v, 8);
        if (col == 0) out[base + w * 16 + quad * 4 + r] = v + b2v;
    }
}

// ---------------- launch ----------------

extern "C" void kernel_launch(void* const* d_in, const int* in_sizes, int n_in,
                              void* d_out, int out_size, void* d_ws, size_t ws_size,
                              hipStream_t stream) {
    const float* x            = (const float*)d_in[0];
    const int*   edge_index   = (const int*)d_in[1];
    const float* edge_attr    = (const float*)d_in[2];
    const float* manual_gamma = (const float*)d_in[3];
    const float* manual_beta  = (const float*)d_in[4];
    const float* embed_W      = (const float*)d_in[5];
    const float* embed_b      = (const float*)d_in[6];
    const float* ln_gamma     = (const float*)d_in[7];
    const float* ln_beta      = (const float*)d_in[8];
    const float* lin_W        = (const float*)d_in[9];
    const float* lin_edge_W   = (const float*)d_in[10];
    const float* att_src      = (const float*)d_in[11];
    const float* att_dst      = (const float*)d_in[12];
    const float* att_edge     = (const float*)d_in[13];
    const float* gat_bias     = (const float*)d_in[14];
    const float* head_W1      = (const float*)d_in[15];
    const float* head_b1      = (const float*)d_in[16];
    const float* head_W2      = (const float*)d_in[17];
    const float* head_b2      = (const float*)d_in[18];
    float* out = (float*)d_out;

    const int* src = edge_index;
    const int* dst = edge_index + EE;

    char* ws = (char*)d_ws;
    size_t off = 0;
    auto alloc = [&](size_t bytes) {
        void* p = ws + off;
        off += (bytes + 255) & ~(size_t)255;
        return p;
    };
    int*   deg        = (int*)alloc(NN * 4);
    int*   hist       = (int*)alloc(128 * 4);
    int*   binBase    = (int*)alloc(128 * 4);
    int*   edgeBase   = (int*)alloc(128 * 4);
    int*   binCnt     = (int*)alloc(128 * 4);
    int*   rankA      = (int*)alloc(NN * 4);
    int*   row_ptr    = (int*)alloc((NN + 1) * 4);
    int*   cnt        = (int*)alloc(NN * 4);
    int2*  sedge      = (int2*)alloc((size_t)EE * 8);
    int*   srcc       = (int*)alloc((size_t)EE * 4);
    float* aeF        = (float*)alloc((size_t)LL * EE * 8);
    float* vs         = (float*)alloc(LL * 128 * 4);
    float* vvd        = (float*)alloc(LL * 128 * 4);
    float* asA        = (float*)alloc((size_t)NN * 2 * 4);
    float* asB        = (float*)alloc((size_t)NN * 2 * 4);
    float* adA        = (float*)alloc((size_t)NN * 2 * 4);
    float* adB        = (float*)alloc((size_t)NN * 2 * 4);
    unsigned short* hmA   = (unsigned short*)alloc((size_t)NN * 64 * 2);
    unsigned short* hmB   = (unsigned short*)alloc((size_t)NN * 64 * 2);
    unsigned short* uvbuf = (unsigned short*)alloc((size_t)NN * 128 * 2);
    unsigned short* gBhi  = (unsigned short*)alloc((size_t)7 * 128 * 64 * 2);
    unsigned short* gBlo  = (unsigned short*)alloc((size_t)7 * 128 * 64 * 2);
    unsigned short* w1chi = (unsigned short*)alloc(64 * 32 * 2);
    unsigned short* w1clo = (unsigned short*)alloc(64 * 32 * 2);
    unsigned short* aeBhi = (unsigned short*)alloc(64 * 8 * 2);
    unsigned short* aeBlo = (unsigned short*)alloc(64 * 8 * 2);
    if (off > ws_size) return;  // insufficient workspace — fail visibly

    smallprep_kernel<<<47, 256, 0, stream>>>(lin_W, head_W1, lin_edge_W, att_edge,
                                             att_src, att_dst, gBhi, gBlo, aeBhi, aeBlo,
                                             vs, vvd, w1chi, w1clo, deg, hist, binCnt);
    deg_kernel<<<EE / 1024, 256, 0, stream>>>(dst, deg);
    hist_kernel<<<NN / 256, 256, 0, stream>>>(deg, hist);
    binscan_kernel<<<1, 128, 0, stream>>>(hist, binBase, edgeBase);
    rank_kernel<<<NN / 256, 256, 0, stream>>>(deg, binBase, edgeBase, binCnt,
                                              rankA, row_ptr, cnt);
    fill_kernel<<<EE / 256, 256, 0, stream>>>(src, dst, rankA, row_ptr, cnt, sedge);
    ae_csr_kernel<<<EE / 256, 256, 0, stream>>>(edge_attr, sedge, aeBhi, aeBlo, aeF, srcc);
    embed_ln_kernel<<<NN / 4, 256, 0, stream>>>(x, embed_W, embed_b, ln_gamma, ln_beta,
                                                manual_gamma, manual_beta, vs, vvd,
                                                rankA, hmA, asA, adA);

    for (int l = 0; l < LL; ++l) {
        const unsigned short* hin = (l & 1) ? hmB : hmA;
        unsigned short* hout = (l & 1) ? hmA : hmB;
        const float* asi = (l & 1) ? asB : asA;
        float* aso = (l & 1) ? asA : asB;
        const float* adi = (l & 1) ? adB : adA;
        float* ado = (l & 1) ? adA : adB;
        const float* aeLl = aeF + (size_t)l * EE * 2;
        if (l < LL - 1) {
            fused_post<<<NN / 64, 512, 0, stream>>>(
                hin, asi, adi, aeLl, srcc, row_ptr,
                gBhi + (size_t)l * 128 * 64, gBlo + (size_t)l * 128 * 64,
                gat_bias + l * 64, ln_gamma + (l + 1) * 64, ln_beta + (l + 1) * 64,
                manual_gamma + (l + 1) * 64, manual_beta + (l + 1) * 64,
                vs + (l + 1) * 128, vvd + (l + 1) * 128, hout, aso, ado);
        } else {
            fused_uv<<<NN / 64, 512, 0, stream>>>(
                hin, asi, adi, aeLl, srcc, row_ptr,
                gBhi + (size_t)l * 128 * 64, gBlo + (size_t)l * 128 * 64,
                gat_bias + l * 64, gBhi + (size_t)6 * 128 * 64,
                gBlo + (size_t)6 * 128 * 64, uvbuf);
        }
    }

    head2_kernel<<<EE / 64, 256, 0, stream>>>(uvbuf, src, dst, rankA, edge_attr,
                                              w1chi, w1clo, head_b1, head_W2,
                                              head_b2, out);
}

// Round 14
// 422.776 us; speedup vs baseline: 1.3931x; 1.3931x over previous
//
#include <hip/hip_runtime.h>
#include <hip/hip_bf16.h>
#include <math.h>

#define NN 32768
#define EE 524288
#define LL 6

typedef __attribute__((ext_vector_type(8))) short short8;
typedef __attribute__((ext_vector_type(4))) float floatx4;
typedef __attribute__((ext_vector_type(4))) float fx4;
typedef __attribute__((ext_vector_type(2))) float fx2;

union U16x8 { short8 v; unsigned short u[8]; };

__device__ __forceinline__ unsigned short f2bf(float x) {
    union { float f; unsigned int u; } v; v.f = x;
    unsigned int r = v.u + 0x7fffu + ((v.u >> 16) & 1u);
    return (unsigned short)(r >> 16);
}
__device__ __forceinline__ float bf2f(unsigned short h) {
    union { unsigned int u; float f; } v; v.u = (unsigned int)h << 16;
    return v.f;
}

// ---------------- preprocessing ----------------

__global__ void deg_kernel(const int* __restrict__ dst, int* __restrict__ deg) {
    int i = (blockIdx.x * 256 + threadIdx.x) * 4;
    int4 d = *(const int4*)(dst + i);
    atomicAdd(&deg[d.x], 1);
    atomicAdd(&deg[d.y], 1);
    atomicAdd(&deg[d.z], 1);
    atomicAdd(&deg[d.w], 1);
}

// degree histogram, LDS-privatized: <=128 global atomics per block (no contention)
__global__ __launch_bounds__(256) void hist_kernel(const int* __restrict__ deg,
                                                   int* __restrict__ hist) {
    __shared__ int lcnt[128];
    int tid = threadIdx.x;
    if (tid < 128) lcnt[tid] = 0;
    __syncthreads();
    int n = blockIdx.x * 256 + tid;
    int b = deg[n]; b = b > 127 ? 127 : b;
    atomicAdd(&lcnt[b], 1);
    __syncthreads();
    if (tid < 128 && lcnt[tid] > 0) atomicAdd(&hist[tid], lcnt[tid]);
}

// exclusive scans of node-count and edge-count per bin
__global__ __launch_bounds__(128) void binscan_kernel(const int* __restrict__ hist,
                                                      int* __restrict__ binBase,
                                                      int* __restrict__ edgeBase) {
    if (threadIdx.x == 0) {
        int accN = 0, accE = 0;
        for (int b = 0; b < 128; ++b) {
            binBase[b] = accN;
            edgeBase[b] = accE;
            int c = hist[b];
            accN += c;
            accE += c * b;
        }
    }
}

// rank assignment, LDS-privatized: block grabs one per-bin base via a single
// global atomic, threads add their LDS-local index. Permuted row_ptr is closed
// form (all nodes in a bin share one degree). Also zeroes per-rank fill counters.
__global__ __launch_bounds__(256) void rank_kernel(
    const int* __restrict__ deg, const int* __restrict__ binBase,
    const int* __restrict__ edgeBase, int* __restrict__ binCnt,
    int* __restrict__ rank, int* __restrict__ row_ptrP, int* __restrict__ cnt) {
    __shared__ int lcnt[128], lbase[128];
    int tid = threadIdx.x;
    if (tid < 128) lcnt[tid] = 0;
    __syncthreads();
    int n = blockIdx.x * 256 + tid;
    int b = deg[n]; b = b > 127 ? 127 : b;
    int li = atomicAdd(&lcnt[b], 1);
    __syncthreads();
    if (tid < 128 && lcnt[tid] > 0) lbase[tid] = atomicAdd(&binCnt[tid], lcnt[tid]);
    __syncthreads();
    int r = binBase[b] + lbase[b] + li;
    rank[n] = r;
    row_ptrP[r] = edgeBase[b] + (r - binBase[b]) * b;
    cnt[r] = 0;
    if (n == 0) row_ptrP[NN] = EE;
}

// CSR fill in rank space: 8-B scatter {edge id, rank[src]}
__global__ void fill_kernel(const int* __restrict__ src, const int* __restrict__ dst,
                            const int* __restrict__ rank, const int* __restrict__ row_ptrP,
                            int* __restrict__ cnt, int2* __restrict__ sedge) {
    int e = blockIdx.x * 256 + threadIdx.x;
    if (e >= EE) return;
    int rd = rank[dst[e]];
    int pos = row_ptrP[rd] + atomicAdd(&cnt[rd], 1);
    sedge[pos] = make_int2(e, rank[src[e]]);
}

// One prep kernel: blocks 0..6 = wprep tiles; block 7 = aeB frags + w1c;
// blocks 8..13 = vsmake[l]; blocks 14..45 = zero deg; block 46 = zero hist/binCnt
__global__ __launch_bounds__(256) void smallprep_kernel(
    const float* __restrict__ lin_W, const float* __restrict__ head_W1,
    const float* __restrict__ lin_edge_W, const float* __restrict__ att_edge,
    const float* __restrict__ att_src, const float* __restrict__ att_dst,
    unsigned short* __restrict__ gBhi, unsigned short* __restrict__ gBlo,
    unsigned short* __restrict__ aeBhi, unsigned short* __restrict__ aeBlo,
    float* __restrict__ vs, float* __restrict__ vvd,
    unsigned short* __restrict__ w1chi, unsigned short* __restrict__ w1clo,
    int* __restrict__ deg, int* __restrict__ hist, int* __restrict__ binCnt) {
    __shared__ float svb[384];
    int bb = blockIdx.x;
    int tid = threadIdx.x;
    if (bb < 7) {
        unsigned short* dh = gBhi + (size_t)bb * 128 * 64;
        unsigned short* dl = gBlo + (size_t)bb * 128 * 64;
        if (bb < 6) {
            int n2 = tid & 63, kh = tid >> 6;
            U16x8 hh[4], ll[4];
            for (int kk = 0; kk < 32; ++kk) {
                int j = kh * 32 + kk;
                int h = j >> 6, k = j & 63;
                float wv = 0.5f * lin_W[((size_t)bb * 64 + k) * 128 + h * 64 + n2];
                unsigned short h16 = f2bf(wv);
                hh[kk >> 3].u[kk & 7] = h16;
                ll[kk >> 3].u[kk & 7] = f2bf(wv - bf2f(h16));
            }
#pragma unroll
            for (int c = 0; c < 4; ++c) {
                int cg = kh * 4 + c;
                int off = n2 * 128 + ((cg ^ (n2 & 15)) << 3);
                *(short8*)(dh + off) = hh[c].v;
                *(short8*)(dl + off) = ll[c].v;
            }
        } else {
            int n = tid & 127, kh = tid >> 7;
            U16x8 hh[4], ll[4];
            for (int kk = 0; kk < 32; ++kk) {
                int k = kh * 32 + kk;
                float wv = (n < 64) ? head_W1[k * 64 + n] : head_W1[(64 + k) * 64 + (n - 64)];
                unsigned short h16 = f2bf(wv);
                hh[kk >> 3].u[kk & 7] = h16;
                ll[kk >> 3].u[kk & 7] = f2bf(wv - bf2f(h16));
            }
#pragma unroll
            for (int c = 0; c < 4; ++c) {
                int cg = kh * 4 + c;
                int off = n * 64 + ((cg ^ (n & 7)) << 3);
                *(short8*)(dh + off) = hh[c].v;
                *(short8*)(dl + off) = ll[c].v;
            }
        }
    } else if (bb == 7) {
        for (int t = tid; t < 384; t += 256) {
            int l = t / 64; int r = t & 63; int ed = r >> 1; int hh = r & 1;
            const float* w = lin_edge_W + l * 32 * 128 + ed * 128 + hh * 64;
            const float* a = att_edge + l * 128 + hh * 64;
            float s = 0.f;
#pragma unroll 8
            for (int c = 0; c < 64; ++c) s += w[c] * a[c];
            svb[t] = s;
        }
        int n = tid & 63, kc = tid >> 6;
#pragma unroll
        for (int j = 0; j < 8; ++j) {
            int k = kc * 8 + j;
            float wv = head_W1[(128 + k) * 64 + n];
            unsigned short h16 = f2bf(wv);
            w1chi[n * 32 + k] = h16;
            w1clo[n * 32 + k] = f2bf(wv - bf2f(h16));
        }
        __syncthreads();
        if (tid < 64) {
            int n2 = tid & 15, q = tid >> 4;
            U16x8 hi, lo;
#pragma unroll
            for (int i = 0; i < 8; ++i) {
                int k = q * 8 + i;
                float val = (n2 < 12) ? svb[(n2 >> 1) * 64 + k * 2 + (n2 & 1)] : 0.f;
                unsigned short h16 = f2bf(val);
                hi.u[i] = h16;
                lo.u[i] = f2bf(val - bf2f(h16));
            }
            *(short8*)(aeBhi + tid * 8) = hi.v;
            *(short8*)(aeBlo + tid * 8) = lo.v;
        }
    } else if (bb < 14) {
        int l = bb - 8;
        int sel = tid >> 7, idx = tid & 127;
        int h = idx >> 6, k = idx & 63;
        const float* att = (sel ? att_dst : att_src) + l * 128 + h * 64;
        const float* wr = lin_W + ((size_t)l * 64 + k) * 128 + h * 64;
        float s = 0.f;
#pragma unroll 8
        for (int c = 0; c < 64; ++c) s += wr[c] * att[c];
        (sel ? vvd : vs)[l * 128 + idx] = s;
    } else if (bb < 46) {
        int i = (bb - 14) * 1024 + tid * 4;
        *(int4*)(deg + i) = make_int4(0, 0, 0, 0);
    } else {
        if (tid < 128) { hist[tid] = 0; binCnt[tid] = 0; }
    }
}

// CSR-order a_e: gathers edge_attr rows (random 128-B, L3-backed), MFMA for all 12
// dots. Writes srcc (rank-space, 4 B/edge) + per-layer float2 aeF (8 B/edge).
__global__ __launch_bounds__(256) void ae_csr_kernel(
    const float* __restrict__ edge_attr, const int2* __restrict__ sedge,
    const unsigned short* __restrict__ aeBhi, const unsigned short* __restrict__ aeBlo,
    float* __restrict__ aeF, int* __restrict__ srcc) {
    __shared__ float tr[4][64 * 13];
    int tid = threadIdx.x;
    int w = tid >> 6, lane = tid & 63;
    int p0 = blockIdx.x * 256 + w * 64;
    short8 bhi = *(const short8*)(aeBhi + lane * 8);
    short8 blo = *(const short8*)(aeBlo + lane * 8);
    int r = lane & 15, q = lane >> 4;
    float* trw = tr[w];
#pragma unroll
    for (int t = 0; t < 4; ++t) {
        int eg = sedge[p0 + t * 16 + r].x;
        const fx4* p = (const fx4*)(edge_attr + (size_t)eg * 32 + q * 8);
        fx4 f0 = p[0], f1 = p[1];
        float av[8] = {f0.x, f0.y, f0.z, f0.w, f1.x, f1.y, f1.z, f1.w};
        U16x8 hi, lo;
#pragma unroll
        for (int jj = 0; jj < 8; ++jj) {
            unsigned short h16 = f2bf(av[jj]);
            hi.u[jj] = h16;
            lo.u[jj] = f2bf(av[jj] - bf2f(h16));
        }
        floatx4 acc = {};
        acc = __builtin_amdgcn_mfma_f32_16x16x32_bf16(lo.v, bhi, acc, 0, 0, 0);
        acc = __builtin_amdgcn_mfma_f32_16x16x32_bf16(hi.v, blo, acc, 0, 0, 0);
        acc = __builtin_amdgcn_mfma_f32_16x16x32_bf16(hi.v, bhi, acc, 0, 0, 0);
        if (r < 12) {
#pragma unroll
            for (int rr = 0; rr < 4; ++rr)
                trw[(t * 16 + q * 4 + rr) * 13 + r] = acc[rr];
        }
    }
    // same-wave DS order: no barrier needed
    int2 sl = sedge[p0 + lane];
    srcc[p0 + lane] = sl.y;
#pragma unroll
    for (int l = 0; l < LL; ++l) {
        fx2 rec;
        rec.x = trw[lane * 13 + l * 2];
        rec.y = trw[lane * 13 + l * 2 + 1];
        __builtin_nontemporal_store(rec, (fx2*)(aeF + ((size_t)l * EE + p0 + lane) * 2));
    }
}

// embed + layer-0 LN/affine + layer-0 attention dots; outputs scattered to rank space
__global__ __launch_bounds__(256) void embed_ln_kernel(
    const float* __restrict__ x, const float* __restrict__ W, const float* __restrict__ b,
    const float* __restrict__ ln_g, const float* __restrict__ ln_b,
    const float* __restrict__ mg, const float* __restrict__ mb,
    const float* __restrict__ vs0, const float* __restrict__ vd0,
    const int* __restrict__ rank,
    unsigned short* __restrict__ hm_bf, float* __restrict__ a_s, float* __restrict__ a_d) {
    __shared__ float xr[4][64];
    int w = threadIdx.x >> 6, j = threadIdx.x & 63;
    int n = blockIdx.x * 4 + w;
    xr[w][j] = x[(size_t)n * 64 + j];
    __syncthreads();
    float acc = b[j];
#pragma unroll 8
    for (int k = 0; k < 64; ++k) acc += xr[w][k] * W[k * 64 + j];
    float s = acc, sq = acc * acc;
    for (int off = 1; off < 64; off <<= 1) { s += __shfl_xor(s, off); sq += __shfl_xor(sq, off); }
    float mu = s * (1.f / 64.f);
    float var = sq * (1.f / 64.f) - mu * mu;
    float rs = rsqrtf(var + 1e-5f);
    float hm = mg[j] * (ln_g[j] * (acc - mu) * rs + ln_b[j]) + mb[j];
    int rp = rank[n];
    hm_bf[(size_t)rp * 64 + j] = f2bf(hm);
    float s0 = hm * vs0[j], s1 = hm * vs0[64 + j];
    float d0 = hm * vd0[j], d1 = hm * vd0[64 + j];
    for (int off = 1; off < 64; off <<= 1) {
        s0 += __shfl_xor(s0, off); s1 += __shfl_xor(s1, off);
        d0 += __shfl_xor(d0, off); d1 += __shfl_xor(d1, off);
    }
    if (j == 0) {
        a_s[rp * 2] = s0; a_s[rp * 2 + 1] = s1;
        a_d[rp * 2] = d0; a_d[rp * 2 + 1] = d1;
    }
}

__device__ __forceinline__ void fma8h(uint4 pv, float w, float* a) {
    unsigned int u[4] = {pv.x, pv.y, pv.z, pv.w};
#pragma unroll
    for (int q = 0; q < 4; ++q) {
        union { unsigned int x; float f; } lo, hi;
        lo.x = u[q] << 16; hi.x = u[q] & 0xffff0000u;
        a[2 * q]     += w * lo.f;
        a[2 * q + 1] += w * hi.f;
    }
}

// Dual-head aggregation for node n (rank space): 8 lanes per node, lane ch owns
// channel pair ch for BOTH heads.
__device__ __forceinline__ void agg_node2(
    int n, int ch, const uint4* hmv, const float2* as2,
    const float* ad_in, const float* aeLl, const int* srcc,
    const int* row_ptr, float* sg, U16x8& hb0, U16x8& hb1) {
    float2 adn = ((const float2*)ad_in)[n];
    float2 asn = as2[n];
    uint4 pvself = hmv[(size_t)n * 8 + ch];
    int beg = row_ptr[n], end = row_ptr[n + 1];
    int degn = end - beg;
    float acc0[8] = {}, acc1[8] = {};
    float den0 = 0.f, den1 = 0.f, aex = 0.f, aey = 0.f;
    for (int base = 0; base < degn; base += 16) {
        int cnt = degn - base; cnt = cnt > 16 ? 16 : cnt;
        // phase 1: lane stages slots ch and ch+8 of this 16-chunk
#pragma unroll
        for (int pass = 0; pass < 2; ++pass) {
            int s = pass * 8 + ch;
            float w0v = 0.f, w1v = 0.f;
            int sval = 0;
            if (s < cnt) {
                int idx = beg + base + s;
                int sv = srcc[idx];
                fx2 ae = *(const fx2*)(aeLl + (size_t)idx * 2);
                float2 as = as2[sv];
                aex += ae.x; aey += ae.y;
                float al0 = as.x + adn.x + ae.x; al0 = al0 > 0.f ? al0 : 0.2f * al0;
                float al1 = as.y + adn.y + ae.y; al1 = al1 > 0.f ? al1 : 0.2f * al1;
                w0v = __expf(al0);
                w1v = __expf(al1);
                sval = sv;
            }
            float4 st;
            st.x = __int_as_float(sval); st.y = w0v; st.z = w1v; st.w = 0.f;
            *(float4*)(sg + s * 4) = st;   // same-wave in-order DS pipe
        }
        // phase 2: 8 slots per step; group of 8 lanes fetches one full node row
        int c8 = (cnt + 7) & ~7;
        for (int s = 0; s < c8; s += 8) {
            float4 m[8];
#pragma unroll
            for (int u = 0; u < 8; ++u) m[u] = *(const float4*)(sg + (s + u) * 4);
            uint4 p[8];
#pragma unroll
            for (int u = 0; u < 8; ++u) p[u] = hmv[(size_t)__float_as_int(m[u].x) * 8 + ch];
#pragma unroll
            for (int u = 0; u < 8; ++u) {
                den0 += m[u].y; fma8h(p[u], m[u].y, acc0);
                den1 += m[u].z; fma8h(p[u], m[u].z, acc1);
            }
        }
    }
    // reduce aex/aey over the 8-lane group
#pragma unroll
    for (int m2 = 1; m2 < 8; m2 <<= 1) {
        aex += __shfl_xor(aex, m2);
        aey += __shfl_xor(aey, m2);
    }
    float invd = 1.f / fmaxf((float)degn, 1.f);
    float al0 = asn.x + adn.x + aex * invd; al0 = al0 > 0.f ? al0 : 0.2f * al0;
    float al1 = asn.y + adn.y + aey * invd; al1 = al1 > 0.f ? al1 : 0.2f * al1;
    float ws0 = __expf(al0), ws1 = __expf(al1);
    den0 += ws0; den1 += ws1;
    fma8h(pvself, ws0, acc0);
    fma8h(pvself, ws1, acc1);
    float inv0 = 1.f / (den0 + 1e-16f), inv1 = 1.f / (den1 + 1e-16f);
#pragma unroll
    for (int q = 0; q < 8; ++q) {
        hb0.u[q] = f2bf(acc0[q] * inv0);
        hb1.u[q] = f2bf(acc1[q] * inv1);
    }
}

// ---------------- fused layer (0..4): rank space; heavy blocks scheduled first ----
__global__ __launch_bounds__(512) void fused_post(
    const unsigned short* __restrict__ hm_in, const float* __restrict__ as_in,
    const float* __restrict__ ad_in, const float* __restrict__ aeLl,
    const int* __restrict__ srcc, const int* __restrict__ row_ptr,
    const unsigned short* __restrict__ gBhi, const unsigned short* __restrict__ gBlo,
    const float* __restrict__ bias, const float* __restrict__ ln_g,
    const float* __restrict__ ln_b, const float* __restrict__ mg,
    const float* __restrict__ mb, const float* __restrict__ vsn,
    const float* __restrict__ vdn, unsigned short* __restrict__ hm_out,
    float* __restrict__ as_out, float* __restrict__ ad_out) {
    __shared__ char smem[49152];                           // 48 KB
    unsigned short* Ahi = (unsigned short*)smem;           // 16 KB [64][128]
    float* stgAll = (float*)(smem + 16384);                // 16 KB during aggregation
    unsigned short* Bhi = (unsigned short*)(smem + 16384); // aliased after
    unsigned short* Blo = (unsigned short*)(smem + 32768);
    int tid = threadIdx.x;
    int w = tid >> 6, lane = tid & 63;
    int g = lane >> 3, ch = lane & 7;
    const float2* as2 = (const float2*)as_in;
    const uint4* hmv = (const uint4*)hm_in;
    float* sg = stgAll + (w * 8 + g) * 64;   // 16 slots x 4 floats per (wave,group)
    int nb = NN - 64 - blockIdx.x * 64;      // heavy (high-degree) blocks first

    {
        int m = w * 8 + g;
        U16x8 hb0, hb1;
        agg_node2(nb + m, ch, hmv, as2, ad_in, aeLl, srcc, row_ptr, sg, hb0, hb1);
        *(short8*)(Ahi + m * 128 + ((ch ^ (m & 15)) << 3)) = hb0.v;
        *(short8*)(Ahi + m * 128 + (((8 + ch) ^ (m & 15)) << 3)) = hb1.v;
    }
    __syncthreads();   // stg dead; Ahi complete
    {
        const uint4* sh = (const uint4*)gBhi;
        const uint4* sl = (const uint4*)gBlo;
        for (int i = tid; i < 1024; i += 512) {
            ((uint4*)Bhi)[i] = sh[i];
            ((uint4*)Blo)[i] = sl[i];
        }
    }
    __syncthreads();

    if (w < 4) {
        int col = lane & 15, quad = lane >> 4;
        int m = w * 16 + col;
        floatx4 acc[4] = {};
#pragma unroll
        for (int s = 0; s < 4; ++s) {
            int ca = (quad + 4 * s) ^ col;
            short8 ahi = *(const short8*)(Ahi + m * 128 + ca * 8);
#pragma unroll
            for (int t = 0; t < 4; ++t) {
                int off = (t * 16 + col) * 128 + ca * 8;
                short8 bhi = *(const short8*)(Bhi + off);
                short8 blo = *(const short8*)(Blo + off);
                acc[t] = __builtin_amdgcn_mfma_f32_16x16x32_bf16(ahi, blo, acc[t], 0, 0, 0);
                acc[t] = __builtin_amdgcn_mfma_f32_16x16x32_bf16(ahi, bhi, acc[t], 0, 0, 0);
            }
        }
        int nodebase = nb + w * 16;
        float bv[4];
#pragma unroll
        for (int t = 0; t < 4; ++t) bv[t] = bias[t * 16 + col];
        float vsv[4], vsv1[4], vdv[4], vdv1[4], lg[4], lb[4], mgv[4], mbv[4];
#pragma unroll
        for (int t = 0; t < 4; ++t) {
            int c = t * 16 + col;
            vsv[t] = vsn[c]; vsv1[t] = vsn[64 + c];
            vdv[t] = vdn[c]; vdv1[t] = vdn[64 + c];
            lg[t] = ln_g[c]; lb[t] = ln_b[c];
            mgv[t] = mg[c]; mbv[t] = mb[c];
        }
#pragma unroll
        for (int r = 0; r < 4; ++r) {
            int node = nodebase + quad * 4 + r;
            float hv[4];
            float s = 0.f, sq = 0.f;
#pragma unroll
            for (int t = 0; t < 4; ++t) {
                float v = acc[t][r] + bv[t];
                v = v > 0.f ? v : 0.f;
                hv[t] = v;
                s += v; sq += v * v;
            }
            for (int off = 1; off < 16; off <<= 1) { s += __shfl_xor(s, off); sq += __shfl_xor(sq, off); }
            float mu = s * (1.f / 64.f);
            float var = sq * (1.f / 64.f) - mu * mu;
            float rs = rsqrtf(var + 1e-5f);
            float s0 = 0.f, s1 = 0.f, d0 = 0.f, d1 = 0.f;
#pragma unroll
            for (int t = 0; t < 4; ++t) {
                float hmval = mgv[t] * (lg[t] * (hv[t] - mu) * rs + lb[t]) + mbv[t];
                hm_out[(size_t)node * 64 + t * 16 + col] = f2bf(hmval);
                s0 += hmval * vsv[t]; s1 += hmval * vsv1[t];
                d0 += hmval * vdv[t]; d1 += hmval * vdv1[t];
            }
            for (int off = 1; off < 16; off <<= 1) {
                s0 += __shfl_xor(s0, off); s1 += __shfl_xor(s1, off);
                d0 += __shfl_xor(d0, off); d1 += __shfl_xor(d1, off);
            }
            if (col == 0) {
                as_out[node * 2] = s0; as_out[node * 2 + 1] = s1;
                ad_out[node * 2] = d0; ad_out[node * 2 + 1] = d1;
            }
        }
    }
}

// ---------------- fused last layer (rank space): agg -> h=relu(A@B5+b) -> uv ----
__global__ __launch_bounds__(512) void fused_uv(
    const unsigned short* __restrict__ hm_in, const float* __restrict__ as_in,
    const float* __restrict__ ad_in, const float* __restrict__ aeLl,
    const int* __restrict__ srcc, const int* __restrict__ row_ptr,
    const unsigned short* __restrict__ gB5hi, const unsigned short* __restrict__ gB5lo,
    const float* __restrict__ bias,
    const unsigned short* __restrict__ gB6hi, const unsigned short* __restrict__ gB6lo,
    unsigned short* __restrict__ uv) {
    __shared__ char smem[49152];
    unsigned short* Ahi  = (unsigned short*)smem;            // stage1 A: 64x128 (16 KB)
    float* stgAll        = (float*)(smem + 16384);           // agg staging (16 KB, aliased)
    unsigned short* B5hi = (unsigned short*)(smem + 16384);
    unsigned short* B5lo = (unsigned short*)(smem + 32768);
    unsigned short* A2hi = (unsigned short*)smem;            // stage2 A (aliases Ahi)
    unsigned short* A2lo = (unsigned short*)(smem + 8192);
    unsigned short* B6hi = (unsigned short*)(smem + 16384);
    unsigned short* B6lo = (unsigned short*)(smem + 32768);
    int tid = threadIdx.x;
    int w = tid >> 6, lane = tid & 63;
    int g = lane >> 3, ch = lane & 7;
    const float2* as2 = (const float2*)as_in;
    const uint4* hmv = (const uint4*)hm_in;
    float* sg = stgAll + (w * 8 + g) * 64;
    int nb = NN - 64 - blockIdx.x * 64;      // heavy blocks first

    {
        int m = w * 8 + g;
        U16x8 hb0, hb1;
        agg_node2(nb + m, ch, hmv, as2, ad_in, aeLl, srcc, row_ptr, sg, hb0, hb1);
        *(short8*)(Ahi + m * 128 + ((ch ^ (m & 15)) << 3)) = hb0.v;
        *(short8*)(Ahi + m * 128 + (((8 + ch) ^ (m & 15)) << 3)) = hb1.v;
    }
    __syncthreads();
    {
        const uint4* sh = (const uint4*)gB5hi;
        const uint4* sl = (const uint4*)gB5lo;
        for (int i = tid; i < 1024; i += 512) {
            ((uint4*)B5hi)[i] = sh[i];
            ((uint4*)B5lo)[i] = sl[i];
        }
    }
    __syncthreads();

    int col = lane & 15, quad = lane >> 4;
    int m = w * 16 + col;
    floatx4 acc[4] = {};
    if (w < 4) {
#pragma unroll
        for (int s = 0; s < 4; ++s) {
            int ca = (quad + 4 * s) ^ col;
            short8 ahi = *(const short8*)(Ahi + m * 128 + ca * 8);
#pragma unroll
            for (int t = 0; t < 4; ++t) {
                int off = (t * 16 + col) * 128 + ca * 8;
                short8 bhi = *(const short8*)(B5hi + off);
                short8 blo = *(const short8*)(B5lo + off);
                acc[t] = __builtin_amdgcn_mfma_f32_16x16x32_bf16(ahi, blo, acc[t], 0, 0, 0);
                acc[t] = __builtin_amdgcn_mfma_f32_16x16x32_bf16(ahi, bhi, acc[t], 0, 0, 0);
            }
        }
    }
    __syncthreads();  // stage1 LDS (Ahi + B5) fully consumed
    if (w < 4) {
        float bv[4];
#pragma unroll
        for (int t = 0; t < 4; ++t) bv[t] = bias[t * 16 + col];
#pragma unroll
        for (int t = 0; t < 4; ++t) {
            int c = t * 16 + col;
            int cg = c >> 3, cr = c & 7;
#pragma unroll
            for (int r = 0; r < 4; ++r) {
                float v = acc[t][r] + bv[t];
                v = v > 0.f ? v : 0.f;
                int i = w * 16 + quad * 4 + r;
                int off = i * 64 + ((cg ^ (i & 7)) << 3) + cr;
                unsigned short hhv = f2bf(v);
                A2hi[off] = hhv;
                A2lo[off] = f2bf(v - bf2f(hhv));
            }
        }
    }
    for (int i = tid; i < 1024; i += 512) {
        ((uint4*)B6hi)[i] = ((const uint4*)gB6hi)[i];
        ((uint4*)B6lo)[i] = ((const uint4*)gB6lo)[i];
    }
    __syncthreads();

    if (w < 4) {
        floatx4 acc2[8] = {};
#pragma unroll
        for (int s = 0; s < 2; ++s) {
            int ca = (quad + 4 * s) ^ (col & 7);
            short8 a2h = *(const short8*)(A2hi + m * 64 + ca * 8);
            short8 a2l = *(const short8*)(A2lo + m * 64 + ca * 8);
#pragma unroll
            for (int t = 0; t < 8; ++t) {
                int off = (t * 16 + col) * 64 + ca * 8;
                short8 bh = *(const short8*)(B6hi + off);
                short8 bl = *(const short8*)(B6lo + off);
                acc2[t] = __builtin_amdgcn_mfma_f32_16x16x32_bf16(a2l, bh, acc2[t], 0, 0, 0);
                acc2[t] = __builtin_amdgcn_mfma_f32_16x16x32_bf16(a2h, bl, acc2[t], 0, 0, 0);
                acc2[t] = __builtin_amdgcn_mfma_f32_16x16x32_bf16(a2h, bh, acc2[t], 0, 0, 0);
            }
        }
        int nodebase = nb + w * 16;
#pragma unroll
        for (int t = 0; t < 8; ++t)
#pragma unroll
            for (int r = 0; r < 4; ++r)
                uv[(size_t)(nodebase + quad * 4 + r) * 128 + t * 16 + col] = f2bf(acc2[t][r]);
    }
}

// ---------------- edge output head: uv rows looked up via rank[] ----------------
__global__ __launch_bounds__(256) void head2_kernel(
    const unsigned short* __restrict__ uv, const int* __restrict__ src,
    const int* __restrict__ dst, const int* __restrict__ rank,
    const float* __restrict__ edge_attr,
    const unsigned short* __restrict__ w1chi, const unsigned short* __restrict__ w1clo,
    const float* __restrict__ b1, const float* __restrict__ W2,
    const float* __restrict__ b2, float* __restrict__ out) {
    __shared__ float g[64][68];
    __shared__ unsigned short Abf[64 * 40];
    __shared__ unsigned short Bh[64 * 40], Bl[64 * 40];
    __shared__ int sA[64], dA[64];
    int tid = threadIdx.x;
    int base = blockIdx.x * 64;
    if (tid < 64) sA[tid] = rank[src[base + tid]];
    else if (tid < 128) dA[tid - 64] = rank[dst[base + tid - 64]];
    {
        int n = tid >> 2, c = tid & 3;
        *(short8*)(Bh + n * 40 + c * 8) = *(const short8*)(w1chi + n * 32 + c * 8);
        *(short8*)(Bl + n * 40 + c * 8) = *(const short8*)(w1clo + n * 32 + c * 8);
    }
    {
        int e = tid >> 2, q = tid & 3;
        const fx4* p = (const fx4*)(edge_attr + (size_t)(base + e) * 32 + q * 8);
        fx4 f0 = __builtin_nontemporal_load(p);
        fx4 f1 = __builtin_nontemporal_load(p + 1);
        float av[8] = {f0.x, f0.y, f0.z, f0.w, f1.x, f1.y, f1.z, f1.w};
        U16x8 cv;
#pragma unroll
        for (int jj = 0; jj < 8; ++jj) cv.u[jj] = f2bf(av[jj]);
        *(short8*)(Abf + e * 40 + q * 8) = cv.v;
    }
    __syncthreads();
    {
        int e = tid >> 2, q = tid & 3;
        const uint4* su = (const uint4*)(uv + (size_t)sA[e] * 128);
        const uint4* dv = (const uint4*)(uv + (size_t)dA[e] * 128);
        uint4 U0 = su[2 * q], U1 = su[2 * q + 1];
        uint4 V0 = dv[8 + 2 * q], V1 = dv[9 + 2 * q];
        const float4* b1p = (const float4*)(b1 + q * 16);
        float bb[16];
#pragma unroll
        for (int jj = 0; jj < 4; ++jj) {
            float4 b4 = b1p[jj];
            bb[4 * jj] = b4.x; bb[4 * jj + 1] = b4.y; bb[4 * jj + 2] = b4.z; bb[4 * jj + 3] = b4.w;
        }
        unsigned int uw[8] = {U0.x, U0.y, U0.z, U0.w, U1.x, U1.y, U1.z, U1.w};
        unsigned int vw[8] = {V0.x, V0.y, V0.z, V0.w, V1.x, V1.y, V1.z, V1.w};
        float* gr = &g[e][q * 16];
#pragma unroll
        for (int jj = 0; jj < 8; ++jj) {
            gr[2 * jj] = bf2f((unsigned short)(uw[jj] & 0xffff)) +
                         bf2f((unsigned short)(vw[jj] & 0xffff)) + bb[2 * jj];
            gr[2 * jj + 1] = bf2f((unsigned short)(uw[jj] >> 16)) +
                             bf2f((unsigned short)(vw[jj] >> 16)) + bb[2 * jj + 1];
        }
    }
    __syncthreads();

    int lane = tid & 63, w = tid >> 6, col = lane & 15, quad = lane >> 4;
    short8 a = *(const short8*)(Abf + (w * 16 + col) * 40 + quad * 8);
    floatx4 acc[4] = {};
#pragma unroll
    for (int t = 0; t < 4; ++t) {
        int off = (t * 16 + col) * 40 + quad * 8;
        short8 bh = *(const short8*)(Bh + off);
        short8 bl = *(const short8*)(Bl + off);
        acc[t] = __builtin_amdgcn_mfma_f32_16x16x32_bf16(a, bl, acc[t], 0, 0, 0);
        acc[t] = __builtin_amdgcn_mfma_f32_16x16x32_bf16(a, bh, acc[t], 0, 0, 0);
    }
    float sv[4] = {0.f, 0.f, 0.f, 0.f};
#pragma unroll
    for (int t = 0; t < 4; ++t) {
        float w2v = W2[t * 16 + col];
#pragma unroll
        for (int r = 0; r < 4; ++r) {
            float hid = acc[t][r] + g[w * 16 + quad * 4 + r][t * 16 + col];
            hid = hid > 0.f ? hid : 0.f;
            sv[r] += hid * w2v;
        }
    }
    float b2v = b2[0];
#pragma unroll
    for (int r = 0; r < 4; ++r) {
        float v = sv[r];
        v += __shfl_xor(v, 1);
        v += __shfl_xor(v, 2);
        v += __shfl_xor(v, 4);
        v += __shfl_xor(v, 8);
        if (col == 0) out[base + w * 16 + quad * 4 + r] = v + b2v;
    }
}

// ---------------- launch ----------------

extern "C" void kernel_launch(void* const* d_in, const int* in_sizes, int n_in,
                              void* d_out, int out_size, void* d_ws, size_t ws_size,
                              hipStream_t stream) {
    const float* x            = (const float*)d_in[0];
    const int*   edge_index   = (const int*)d_in[1];
    const float* edge_attr    = (const float*)d_in[2];
    const float* manual_gamma = (const float*)d_in[3];
    const float* manual_beta  = (const float*)d_in[4];
    const float* embed_W      = (const float*)d_in[5];
    const float* embed_b      = (const float*)d_in[6];
    const float* ln_gamma     = (const float*)d_in[7];
    const float* ln_beta      = (const float*)d_in[8];
    const float* lin_W        = (const float*)d_in[9];
    const float* lin_edge_W   = (const float*)d_in[10];
    const float* att_src      = (const float*)d_in[11];
    const float* att_dst      = (const float*)d_in[12];
    const float* att_edge     = (const float*)d_in[13];
    const float* gat_bias     = (const float*)d_in[14];
    const float* head_W1      = (const float*)d_in[15];
    const float* head_b1      = (const float*)d_in[16];
    const float* head_W2      = (const float*)d_in[17];
    const float* head_b2      = (const float*)d_in[18];
    float* out = (float*)d_out;

    const int* src = edge_index;
    const int* dst = edge_index + EE;

    char* ws = (char*)d_ws;
    size_t off = 0;
    auto alloc = [&](size_t bytes) {
        void* p = ws + off;
        off += (bytes + 255) & ~(size_t)255;
        return p;
    };
    int*   deg        = (int*)alloc(NN * 4);
    int*   hist       = (int*)alloc(128 * 4);
    int*   binBase    = (int*)alloc(128 * 4);
    int*   edgeBase   = (int*)alloc(128 * 4);
    int*   binCnt     = (int*)alloc(128 * 4);
    int*   rankA      = (int*)alloc(NN * 4);
    int*   row_ptr    = (int*)alloc((NN + 1) * 4);
    int*   cnt        = (int*)alloc(NN * 4);
    int2*  sedge      = (int2*)alloc((size_t)EE * 8);
    int*   srcc       = (int*)alloc((size_t)EE * 4);
    float* aeF        = (float*)alloc((size_t)LL * EE * 8);
    float* vs         = (float*)alloc(LL * 128 * 4);
    float* vvd        = (float*)alloc(LL * 128 * 4);
    float* asA        = (float*)alloc((size_t)NN * 2 * 4);
    float* asB        = (float*)alloc((size_t)NN * 2 * 4);
    float* adA        = (float*)alloc((size_t)NN * 2 * 4);
    float* adB        = (float*)alloc((size_t)NN * 2 * 4);
    unsigned short* hmA   = (unsigned short*)alloc((size_t)NN * 64 * 2);
    unsigned short* hmB   = (unsigned short*)alloc((size_t)NN * 64 * 2);
    unsigned short* uvbuf = (unsigned short*)alloc((size_t)NN * 128 * 2);
    unsigned short* gBhi  = (unsigned short*)alloc((size_t)7 * 128 * 64 * 2);
    unsigned short* gBlo  = (unsigned short*)alloc((size_t)7 * 128 * 64 * 2);
    unsigned short* w1chi = (unsigned short*)alloc(64 * 32 * 2);
    unsigned short* w1clo = (unsigned short*)alloc(64 * 32 * 2);
    unsigned short* aeBhi = (unsigned short*)alloc(64 * 8 * 2);
    unsigned short* aeBlo = (unsigned short*)alloc(64 * 8 * 2);
    if (off > ws_size) return;  // insufficient workspace — fail visibly

    smallprep_kernel<<<47, 256, 0, stream>>>(lin_W, head_W1, lin_edge_W, att_edge,
                                             att_src, att_dst, gBhi, gBlo, aeBhi, aeBlo,
                                             vs, vvd, w1chi, w1clo, deg, hist, binCnt);
    deg_kernel<<<EE / 1024, 256, 0, stream>>>(dst, deg);
    hist_kernel<<<NN / 256, 256, 0, stream>>>(deg, hist);
    binscan_kernel<<<1, 128, 0, stream>>>(hist, binBase, edgeBase);
    rank_kernel<<<NN / 256, 256, 0, stream>>>(deg, binBase, edgeBase, binCnt,
                                              rankA, row_ptr, cnt);
    fill_kernel<<<EE / 256, 256, 0, stream>>>(src, dst, rankA, row_ptr, cnt, sedge);
    ae_csr_kernel<<<EE / 256, 256, 0, stream>>>(edge_attr, sedge, aeBhi, aeBlo, aeF, srcc);
    embed_ln_kernel<<<NN / 4, 256, 0, stream>>>(x, embed_W, embed_b, ln_gamma, ln_beta,
                                                manual_gamma, manual_beta, vs, vvd,
                                                rankA, hmA, asA, adA);

    for (int l = 0; l < LL; ++l) {
        const unsigned short* hin = (l & 1) ? hmB : hmA;
        unsigned short* hout = (l & 1) ? hmA : hmB;
        const float* asi = (l & 1) ? asB : asA;
        float* aso = (l & 1) ? asA : asB;
        const float* adi = (l & 1) ? adB : adA;
        float* ado = (l & 1) ? adA : adB;
        const float* aeLl = aeF + (size_t)l * EE * 2;
        if (l < LL - 1) {
            fused_post<<<NN / 64, 512, 0, stream>>>(
                hin, asi, adi, aeLl, srcc, row_ptr,
                gBhi + (size_t)l * 128 * 64, gBlo + (size_t)l * 128 * 64,
                gat_bias + l * 64, ln_gamma + (l + 1) * 64, ln_beta + (l + 1) * 64,
                manual_gamma + (l + 1) * 64, manual_beta + (l + 1) * 64,
                vs + (l + 1) * 128, vvd + (l + 1) * 128, hout, aso, ado);
        } else {
            fused_uv<<<NN / 64, 512, 0, stream>>>(
                hin, asi, adi, aeLl, srcc, row_ptr,
                gBhi + (size_t)l * 128 * 64, gBlo + (size_t)l * 128 * 64,
                gat_bias + l * 64, gBhi + (size_t)6 * 128 * 64,
                gBlo + (size_t)6 * 128 * 64, uvbuf);
        }
    }

    head2_kernel<<<EE / 64, 256, 0, stream>>>(uvbuf, src, dst, rankA, edge_attr,
                                              w1chi, w1clo, head_b1, head_W2,
                                              head_b2, out);
}